// Round 2
// baseline (795.695 us; speedup 1.0000x reference)
//
#include <hip/hip_runtime.h>
#include <hip/hip_bf16.h>
#include <hip/hip_cooperative_groups.h>

namespace cg = cooperative_groups;

#define N0   3000
#define E0   48000
#define K1N  1500
#define K2N  750
#define HID  128
#define CAP  128
#define LD1  1536  // padded leading dim for A1
#define LD2  768   // padded leading dim for A2/Ac
#define BM   32    // row-tile for k_yw2
#define ATS  36    // transposed X-tile stride (BM+4, bank-spread)
#define RCAP 1536  // CSR row capacity (>= max possible nnz = K1N)
#define TKT  1024  // k_topk threads (16 waves on one CU)
#define GRD  256   // mega-kernel grid (1 block per CU, cooperative)
#define MBT  1024  // mega-kernel block threads

__device__ __forceinline__ unsigned fkey(float f) {
  unsigned u = __float_as_uint(f);
  return (u & 0x80000000u) ? ~u : (u | 0x80000000u);
}
__device__ __forceinline__ float inv_fkey(unsigned u) {
  unsigned v = (u & 0x80000000u) ? (u & 0x7FFFFFFFu) : ~u;
  return __uint_as_float(v);
}

// ---------------- workspace layout (float units) ----------------
constexpr size_t F_A1    = 0;                          // K1N*LD1
constexpr size_t F_SCR   = F_A1 + (size_t)K1N * LD1;   // Ac (int16) = K1N*LD2 shorts
constexpr size_t SCR_SZ  = 1155072;                    // plenty
constexpr size_t F_A2    = F_SCR + SCR_SZ;             // K2N*LD2
constexpr size_t F_YSC   = F_A2 + (size_t)K2N * LD2;   // N0*HID
constexpr size_t F_H0    = F_YSC + (size_t)N0 * HID;   // N0*HID
constexpr size_t F_H1    = F_H0 + (size_t)N0 * HID;    // K1N*HID
constexpr size_t F_H2    = F_H1 + (size_t)K1N * HID;   // K2N*HID
constexpr size_t F_U1    = F_H2 + (size_t)K2N * HID;   // (hole, kept for layout)
constexpr size_t F_U1B   = F_U1 + (size_t)K1N * HID;   // K1N*HID
constexpr size_t F_YF    = F_U1B + (size_t)K1N * HID;  // N0*3
constexpr size_t F_SCORE = F_YF + (size_t)N0 * 3;      // N0
constexpr size_t F_GATE1 = F_SCORE + N0;               // K1N  } contiguous zero fill
constexpr size_t F_GATE2 = F_GATE1 + K1N;              // K2N  }
constexpr size_t F_DIS0  = F_GATE2 + K2N;              // (unused)
constexpr size_t F_DIS1  = F_DIS0 + N0;                // K1N
constexpr size_t F_DIS2  = F_DIS1 + K1N;               // K2N
constexpr size_t F_PERM1 = F_DIS2 + K2N;               // K1N (int) } contiguous 0 fill
constexpr size_t F_PERM2 = F_PERM1 + K1N;              // K2N (int) }
constexpr size_t F_INV1  = F_PERM2 + K2N;              // N0  (int) } contiguous -1 fill
constexpr size_t F_INV2  = F_INV1 + N0;                // K1N (int) }
constexpr size_t F_CNTI  = F_INV2 + K1N;               // N0  (int) } contiguous 0 fill
constexpr size_t F_CNTO  = F_CNTI + N0;                // N0  (int) }
constexpr size_t F_SELF  = F_CNTO + N0;                // N0  (int) }
constexpr size_t F_CI    = F_SELF + N0;                // N0*CAP (int)
constexpr size_t F_CO    = F_CI + (size_t)N0 * CAP;    // N0*CAP (int)
constexpr size_t F_CSRN  = F_CO + (size_t)N0 * CAP;    // K1N (int)
constexpr size_t F_CSRK  = F_CSRN + K1N;               // K1N*RCAP (int)
constexpr size_t F_CSRW  = F_CSRK + (size_t)K1N * RCAP;// K1N*RCAP (float)
constexpr size_t F_END   = F_CSRW + (size_t)K1N * RCAP;

// ======================================================================
// ===================  FALLBACK (round-1 verified) kernels =============
// ======================================================================

__global__ void k_init(float* __restrict__ A1, float* __restrict__ gate,
                       int* __restrict__ perm, int* __restrict__ inv,
                       int* __restrict__ cnt, float* __restrict__ outlab) {
  int i = blockIdx.x * blockDim.x + threadIdx.x, st = gridDim.x * blockDim.x;
  for (int j = i; j < K1N * LD1; j += st) A1[j] = 0.0f;
  for (int j = i; j < K1N + K2N; j += st) gate[j] = 0.0f;
  for (int j = i; j < K1N + K2N; j += st) perm[j] = 0;
  for (int j = i; j < N0 + K1N; j += st) inv[j] = -1;
  for (int j = i; j < 3 * N0; j += st) cnt[j] = 0;
  for (int j = i; j < N0 * 29; j += st) outlab[j] = 0.0f;
}

__global__ void k_count(const int* __restrict__ ei, int* cnt_in, int* cnt_out, int* selfc,
                        int* col_in, int* col_out) {
  int e = blockIdx.x * blockDim.x + threadIdx.x;
  if (e >= E0) return;
  int s = ei[e], d = ei[E0 + e];
  if (s == d) { atomicAdd(&selfc[d], 1); return; }
  int a = atomicAdd(&cnt_in[d], 1);
  if (a < CAP) col_in[d * CAP + a] = s;
  int b = atomicAdd(&cnt_out[s], 1);
  if (b < CAP) col_out[s * CAP + b] = d;
}

__global__ __launch_bounds__(256) void k_yw2(const float* __restrict__ X,
                                             const float* __restrict__ X2,
                                             const int* __restrict__ inv2c,
                                             int Kin, int nsrc, int n,
                                             const float* __restrict__ Wm,
                                             const int* __restrict__ perm,
                                             const float* __restrict__ gate,
                                             const float* __restrict__ dis,
                                             const int* __restrict__ cntd,
                                             const int* __restrict__ selfd,
                                             float* __restrict__ Ysc) {
  __shared__ float Wt[32 * HID];
  __shared__ float Xt[32 * ATS];
  int t = threadIdx.x;
  int r0 = blockIdx.x * BM;
  int f4 = (t & 31) * 4;
  int rg = t >> 5;
  float4 acc0 = {0,0,0,0}, acc1 = {0,0,0,0}, acc2 = {0,0,0,0}, acc3 = {0,0,0,0};
  for (int kb = 0; kb < Kin; kb += 32) {
    {
      const float4* src = (const float4*)(Wm + (size_t)kb * HID);
      float4* dst = (float4*)Wt;
#pragma unroll
      for (int i = 0; i < 4; ++i) dst[i * 256 + t] = src[i * 256 + t];
    }
    {
      int j = t >> 3;
      int k4 = (t & 7) * 4;
      int r = r0 + j;
      int src_row = (r < n) ? r : (n - 1);
      if (perm) {
        int s = perm[src_row];
        if (s < 0) s = 0;
        if (s >= nsrc) s = nsrc - 1;
        src_row = s;
      }
      float4 xv = *(const float4*)(X + (size_t)src_row * Kin + kb + k4);
      if (X2) {
        int ii = inv2c[src_row];
        if (ii >= 0 && ii < K2N) {
          float4 x2 = *(const float4*)(X2 + (size_t)ii * Kin + kb + k4);
          xv.x += x2.x; xv.y += x2.y; xv.z += x2.z; xv.w += x2.w;
        }
      }
      Xt[(k4 + 0) * ATS + j] = xv.x;
      Xt[(k4 + 1) * ATS + j] = xv.y;
      Xt[(k4 + 2) * ATS + j] = xv.z;
      Xt[(k4 + 3) * ATS + j] = xv.w;
    }
    __syncthreads();
#pragma unroll 4
    for (int kk = 0; kk < 32; ++kk) {
      float4 y = *(const float4*)&Wt[kk * HID + f4];
      float4 a = *(const float4*)&Xt[kk * ATS + rg * 4];
      acc0.x += a.x * y.x; acc0.y += a.x * y.y; acc0.z += a.x * y.z; acc0.w += a.x * y.w;
      acc1.x += a.y * y.x; acc1.y += a.y * y.y; acc1.z += a.y * y.z; acc1.w += a.y * y.w;
      acc2.x += a.z * y.x; acc2.y += a.z * y.y; acc2.z += a.z * y.z; acc2.w += a.z * y.w;
      acc3.x += a.w * y.x; acc3.y += a.w * y.y; acc3.z += a.w * y.z; acc3.w += a.w * y.w;
    }
    __syncthreads();
  }
  int r = r0 + rg * 4;
  float4* accs[4] = {&acc0, &acc1, &acc2, &acc3};
#pragma unroll
  for (int j = 0; j < 4; ++j) {
    int row = r + j;
    if (row >= n) continue;
    float g = gate ? gate[row] : 1.0f;
    float d = dis ? dis[row] : (1.0f / sqrtf((float)(cntd[row] + selfd[row] + 2)));
    float s = d * g;
    float4 a = *accs[j];
    *(float4*)&Ysc[(size_t)row * HID + f4] = make_float4(s * a.x, s * a.y, s * a.z, s * a.w);
  }
}

__global__ void k_gcn_sparse(const float* __restrict__ Ysc, const int* __restrict__ cnt_in,
                             const int* __restrict__ col_in, const int* __restrict__ selfc,
                             const float* __restrict__ bias, const float* __restrict__ p,
                             float* __restrict__ H, float* __restrict__ score) {
  __shared__ float red[HID];
  __shared__ float red2[HID];
  int d = blockIdx.x, f = threadIdx.x;
  int cntu = cnt_in[d];
  int cnt = cntu > CAP ? CAP : cntu;
  float acc = (2.0f + (float)selfc[d]) * Ysc[d * HID + f];
  int e = 0;
  for (; e + 8 <= cnt; e += 8) {
    float y[8];
#pragma unroll
    for (int j = 0; j < 8; ++j) y[j] = Ysc[col_in[d * CAP + e + j] * HID + f];
#pragma unroll
    for (int j = 0; j < 8; ++j) acc += y[j];
  }
  for (; e < cnt; ++e) acc += Ysc[col_in[d * CAP + e] * HID + f];
  float d0 = 1.0f / sqrtf((float)(cntu + selfc[d] + 2));
  float h = tanhf(d0 * acc + bias[f]);
  H[d * HID + f] = h;
  float pv = p[f];
  red[f] = h * pv;
  red2[f] = pv * pv;
  __syncthreads();
  for (int s = 64; s > 0; s >>= 1) {
    if (f < s) { red[f] += red[f + s]; red2[f] += red2[f + s]; }
    __syncthreads();
  }
  if (f == 0) score[d] = tanhf(red[0] * (1.0f / sqrtf(red2[0])));
}

__global__ __launch_bounds__(TKT) void k_topk(const float* __restrict__ score, int n, int K,
                                              int* __restrict__ perm, float* __restrict__ gatec,
                                              int* __restrict__ inv) {
  __shared__ unsigned setA[N0];
  __shared__ unsigned setB[N0];
  __shared__ int hist[256];
  __shared__ int sscan[257];
  __shared__ unsigned pfx_sh;
  __shared__ int rem_sh;
  __shared__ int cnt_sh;
  __shared__ int cgt[48], ceq[48], bgt[48], beq[48];
  int t = threadIdx.x;
  int lane = t & 63, wv = t >> 6;
  unsigned long long below = (lane == 0) ? 0ull : (~0ull >> (64 - lane));
  for (int i = t; i < n; i += TKT) setA[i] = fkey(score[i]);
  __syncthreads();

  unsigned prefix = 0; int rem = K; int m = n;
  unsigned* cur = setA; unsigned* nxt = setB;
  for (int pass = 3; pass >= 0; --pass) {
    if (t < 256) hist[t] = 0;
    __syncthreads();
    for (int i = t; i < m; i += TKT) atomicAdd(&hist[(cur[i] >> (pass * 8)) & 255], 1);
    __syncthreads();
    if (t < 256) { sscan[t] = hist[t]; if (t == 0) sscan[256] = 0; }
    __syncthreads();
    for (int off = 1; off < 256; off <<= 1) {
      int add = 0;
      if (t < 256) add = (t + off < 256) ? sscan[t + off] : 0;
      __syncthreads();
      if (t < 256) sscan[t] += add;
      __syncthreads();
    }
    if (t < 256 && sscan[t] >= rem && sscan[t + 1] < rem) {
      pfx_sh = prefix | ((unsigned)t << (pass * 8));
      rem_sh = rem - sscan[t + 1];
    }
    __syncthreads();
    prefix = pfx_sh; rem = rem_sh;
    if (pass > 0) {
      unsigned dg = (prefix >> (pass * 8)) & 255u;
      if (t == 0) cnt_sh = 0;
      __syncthreads();
      for (int c0 = 0; c0 < m; c0 += TKT) {
        int i = c0 + t;
        unsigned u = (i < m) ? cur[i] : 0u;
        bool match = (i < m) && (((u >> (pass * 8)) & 255u) == dg);
        unsigned long long mm = __ballot(match);
        int cw = (int)__popcll(mm);
        int basew = 0;
        if (lane == 0 && cw) basew = atomicAdd(&cnt_sh, cw);
        basew = __shfl(basew, 0);
        if (match) nxt[basew + (int)__popcll(mm & below)] = u;
      }
      __syncthreads();
      m = cnt_sh;
      unsigned* tmp = cur; cur = nxt; nxt = tmp;
    }
  }
  unsigned uthr = prefix;
  int c_gt = K - rem;
  int NC = (n + 63) >> 6;
  for (int c = wv; c < NC; c += 16) {
    int i = (c << 6) + lane;
    unsigned u = (i < n) ? fkey(score[i]) : 0u;
    bool isgt = (i < n) && (u > uthr);
    bool iseq = (i < n) && (u == uthr);
    unsigned long long mg = __ballot(isgt);
    unsigned long long me = __ballot(iseq);
    if (lane == 0) { cgt[c] = (int)__popcll(mg); ceq[c] = (int)__popcll(me); }
  }
  __syncthreads();
  if (t == 0) {
    int g = 0, e = 0;
    for (int c = 0; c < NC; ++c) { bgt[c] = g; g += cgt[c]; beq[c] = e; e += ceq[c]; }
  }
  __syncthreads();
  for (int c = wv; c < NC; c += 16) {
    int i = (c << 6) + lane;
    unsigned u = (i < n) ? fkey(score[i]) : 0u;
    bool isgt = (i < n) && (u > uthr);
    bool iseq = (i < n) && (u == uthr);
    unsigned long long mg = __ballot(isgt);
    unsigned long long me = __ballot(iseq);
    if (isgt) {
      int pos = bgt[c] + (int)__popcll(mg & below);
      perm[pos] = i; gatec[pos] = inv_fkey(u); inv[i] = pos;
    } else if (iseq) {
      int er = beq[c] + (int)__popcll(me & below);
      if (er < rem) { int pos = c_gt + er; perm[pos] = i; gatec[pos] = inv_fkey(u); inv[i] = pos; }
    }
  }
}

__global__ void k_pairs(const int* __restrict__ cnt_in, const int* __restrict__ col_in,
                        const int* __restrict__ cnt_out, const int* __restrict__ col_out,
                        const int* __restrict__ inv, float* __restrict__ A1) {
  __shared__ int outl[CAP], inl[CAP], invo[CAP], invi[CAP];
  int k = blockIdx.x, t = threadIdx.x;
  int no = cnt_out[k]; if (no > CAP) no = CAP;
  int ni = cnt_in[k];  if (ni > CAP) ni = CAP;
  if (t < no) { int i = col_out[k * CAP + t]; outl[t] = i; invo[t] = inv[i]; }
  if (t < ni) { int j = col_in[k * CAP + t];  inl[t] = j;  invi[t] = inv[j]; }
  __syncthreads();
  int invk = inv[k];
  if (t < ni && invk >= 0) {
    int jj = invi[t];
    if (jj >= 0) atomicAdd(&A1[(size_t)invk * LD1 + jj], 2.0f);
  }
  for (int a = t; a < no; a += blockDim.x) {
    int i = outl[a], ii = invo[a];
    if (ii < 0) continue;
    for (int b = 0; b < ni; ++b) {
      int jj = invi[b];
      if (jj >= 0 && i != inl[b]) atomicAdd(&A1[(size_t)ii * LD1 + jj], 1.0f);
    }
  }
}

__global__ __launch_bounds__(128) void k_a1csr(const float* __restrict__ A1,
                                               int* __restrict__ csr_n,
                                               int* __restrict__ csr_k,
                                               float* __restrict__ csr_w,
                                               float* __restrict__ dis1) {
  __shared__ int cntw[2];
  __shared__ float wsum_sh[2];
  int r = blockIdx.x, t = threadIdx.x;
  const float* arow = A1 + (size_t)r * LD1;
  int wid = t >> 6, lane = t & 63;
  unsigned long long below = (lane == 0) ? 0ull : (~0ull >> (64 - lane));
  int base = 0;
  float wsum = 0.0f;
  int* gk = csr_k + (size_t)r * RCAP;
  float* gw = csr_w + (size_t)r * RCAP;
  for (int c0 = 0; c0 < K1N; c0 += 128) {
    int col = c0 + t;
    float w = (col < K1N) ? arow[col] : 0.0f;
    wsum += w;
    bool nz = (w != 0.0f);
    unsigned long long m = __ballot(nz);
    if (lane == 0) cntw[wid] = (int)__popcll(m);
    __syncthreads();
    int pos = base + (wid ? cntw[0] : 0) + (int)__popcll(m & below);
    if (nz) { gk[pos] = col; gw[pos] = w; }
    base += cntw[0] + cntw[1];
    __syncthreads();
  }
  for (int off = 32; off > 0; off >>= 1) wsum += __shfl_down(wsum, off);
  if (lane == 0) wsum_sh[wid] = wsum;
  __syncthreads();
  if (t == 0) {
    csr_n[r] = base;
    dis1[r] = 1.0f / sqrtf(wsum_sh[0] + wsum_sh[1] + 2.0f);
  }
}

__global__ __launch_bounds__(256) void k_cmp(const float* __restrict__ A1,
                                             const int* __restrict__ perm2,
                                             short* __restrict__ Ac) {
  __shared__ int q[K2N];
  int k = blockIdx.x, t = threadIdx.x;
  for (int i = t; i < K2N; i += 256) {
    int v = perm2[i];
    if (v < 0) v = 0;
    if (v >= K1N) v = K1N - 1;
    q[i] = v;
  }
  __syncthreads();
  const float* row = A1 + (size_t)k * LD1;
  short* dst = Ac + (size_t)k * LD2;
  for (int b = t; b < LD2; b += 256) dst[b] = (b < K2N) ? (short)row[q[b]] : (short)0;
}

__global__ __launch_bounds__(192) void k_sq2(const float* __restrict__ A1,
                                             const short* __restrict__ Ac,
                                             const int* __restrict__ perm2,
                                             const int* __restrict__ csr_n,
                                             const int* __restrict__ csr_k,
                                             const float* __restrict__ csr_w,
                                             float* __restrict__ A2,
                                             float* __restrict__ dis2) {
  __shared__ int klist[K1N];
  __shared__ float wlist[K1N];
  __shared__ float wred[3];
  int a = blockIdx.x, t = threadIdx.x;
  int qa = perm2[a];
  if (qa < 0) qa = 0;
  if (qa >= K1N) qa = K1N - 1;
  const float* arow = A1 + (size_t)qa * LD1;
  int nnz = csr_n[qa];
  {
    const int* gk = csr_k + (size_t)qa * RCAP;
    const float* gw = csr_w + (size_t)qa * RCAP;
    for (int c = t; c < nnz; c += 192) { klist[c] = gk[c]; wlist[c] = gw[c]; }
  }
  __syncthreads();
  int c0 = t * 4;
  float4 acc = make_float4(0.f, 0.f, 0.f, 0.f);
  int p = 0;
  for (; p + 8 <= nnz; p += 8) {
    int kk[8]; float ww[8];
#pragma unroll
    for (int j = 0; j < 8; ++j) { kk[j] = klist[p + j]; ww[j] = wlist[p + j]; }
    short4 v[8];
#pragma unroll
    for (int j = 0; j < 8; ++j) v[j] = *(const short4*)&Ac[(size_t)kk[j] * LD2 + c0];
#pragma unroll
    for (int j = 0; j < 8; ++j) {
      acc.x += ww[j] * (float)v[j].x;
      acc.y += ww[j] * (float)v[j].y;
      acc.z += ww[j] * (float)v[j].z;
      acc.w += ww[j] * (float)v[j].w;
    }
  }
  for (; p < nnz; ++p) {
    int k = klist[p]; float w = wlist[p];
    short4 v = *(const short4*)&Ac[(size_t)k * LD2 + c0];
    acc.x += w * (float)v.x; acc.y += w * (float)v.y;
    acc.z += w * (float)v.z; acc.w += w * (float)v.w;
  }
  float rsum = 0.0f;
  {
    float accv[4] = {acc.x, acc.y, acc.z, acc.w};
    float outv[4];
#pragma unroll
    for (int j = 0; j < 4; ++j) {
      int col = c0 + j;
      float v = 0.0f;
      if (col < K2N && col != a) {
        int qb = perm2[col];
        if (qb < 0) qb = 0;
        if (qb >= K1N) qb = K1N - 1;
        v = accv[j] + 2.0f * arow[qb];
      }
      outv[j] = v;
      rsum += v;
    }
    *(float4*)&A2[(size_t)a * LD2 + c0] = make_float4(outv[0], outv[1], outv[2], outv[3]);
  }
  for (int off = 32; off > 0; off >>= 1) rsum += __shfl_down(rsum, off);
  if ((t & 63) == 0) wred[t >> 6] = rsum;
  __syncthreads();
  if (t == 0) dis2[a] = 1.0f / sqrtf(wred[0] + wred[1] + wred[2] + 2.0f);
}

__global__ __launch_bounds__(128) void k_spmv_csr(const int* __restrict__ csr_n,
                                                  const int* __restrict__ csr_k,
                                                  const float* __restrict__ csr_w,
                                                  const float* __restrict__ Ysc,
                                                  const float* __restrict__ dis,
                                                  const float* __restrict__ bias,
                                                  const float* __restrict__ p,
                                                  float* __restrict__ H,
                                                  float* __restrict__ score, int act) {
  __shared__ int klist[K1N];
  __shared__ float wlist[K1N];
  __shared__ float red[HID];
  __shared__ float red2[HID];
  int r = blockIdx.x, t = threadIdx.x;
  int nnz = csr_n[r];
  {
    const int* gk = csr_k + (size_t)r * RCAP;
    const float* gw = csr_w + (size_t)r * RCAP;
    for (int i = t; i < nnz; i += 128) { klist[i] = gk[i]; wlist[i] = gw[i]; }
  }
  __syncthreads();
  float acc = 0.0f;
  int pp = 0;
  for (; pp + 8 <= nnz; pp += 8) {
    float y[8];
#pragma unroll
    for (int j = 0; j < 8; ++j) y[j] = Ysc[(size_t)klist[pp + j] * HID + t];
#pragma unroll
    for (int j = 0; j < 8; ++j) acc += wlist[pp + j] * y[j];
  }
  for (; pp < nnz; ++pp) acc += wlist[pp] * Ysc[(size_t)klist[pp] * HID + t];
  float zv = dis[r] * (acc + 2.0f * Ysc[(size_t)r * HID + t]) + bias[t];
  float h = act ? tanhf(zv) : zv;
  H[(size_t)r * HID + t] = h;
  if (p) {
    float pv = p[t];
    red[t] = h * pv;
    red2[t] = pv * pv;
    __syncthreads();
    for (int s = 64; s > 0; s >>= 1) {
      if (t < s) { red[t] += red[t + s]; red2[t] += red2[t + s]; }
      __syncthreads();
    }
    if (t == 0) score[r] = tanhf(red[0] * (1.0f / sqrtf(red2[0])));
  }
}

__global__ __launch_bounds__(128) void k_spmv(const float* __restrict__ A, int ncols, int ld,
                                              const float* __restrict__ Ysc,
                                              const float* __restrict__ dis,
                                              const float* __restrict__ bias,
                                              const float* __restrict__ p,
                                              float* __restrict__ H,
                                              float* __restrict__ score, int act) {
  __shared__ int klist[K1N];
  __shared__ float wlist[K1N];
  __shared__ int cntw[2];
  __shared__ float red[HID];
  __shared__ float red2[HID];
  int r = blockIdx.x, t = threadIdx.x;
  const float* arow = A + (size_t)r * ld;
  int wid = t >> 6, lane = t & 63;
  unsigned long long below = (lane == 0) ? 0ull : (~0ull >> (64 - lane));
  int base = 0;
  for (int c0 = 0; c0 < ncols; c0 += 128) {
    int col = c0 + t;
    float w = (col < ncols) ? arow[col] : 0.0f;
    bool nz = (w != 0.0f);
    unsigned long long m = __ballot(nz);
    if (lane == 0) cntw[wid] = (int)__popcll(m);
    __syncthreads();
    int pos = base + (wid ? cntw[0] : 0) + (int)__popcll(m & below);
    if (nz) { klist[pos] = col; wlist[pos] = w; }
    base += cntw[0] + cntw[1];
    __syncthreads();
  }
  int nnz = base;
  float acc = 0.0f;
  int pp = 0;
  for (; pp + 8 <= nnz; pp += 8) {
    float y[8];
#pragma unroll
    for (int j = 0; j < 8; ++j) y[j] = Ysc[(size_t)klist[pp + j] * HID + t];
#pragma unroll
    for (int j = 0; j < 8; ++j) acc += wlist[pp + j] * y[j];
  }
  for (; pp < nnz; ++pp) acc += wlist[pp] * Ysc[(size_t)klist[pp] * HID + t];
  float zv = dis[r] * (acc + 2.0f * Ysc[(size_t)r * HID + t]) + bias[t];
  float h = act ? tanhf(zv) : zv;
  H[(size_t)r * HID + t] = h;
  if (p) {
    float pv = p[t];
    red[t] = h * pv;
    red2[t] = pv * pv;
    __syncthreads();
    for (int s = 64; s > 0; s >>= 1) {
      if (t < s) { red[t] += red[t + s]; red2[t] += red2[t + s]; }
      __syncthreads();
    }
    if (t == 0) score[r] = tanhf(red[0] * (1.0f / sqrtf(red2[0])));
  }
}

__global__ void k_yf(const float* __restrict__ h0, const float* __restrict__ u1b,
                     const int* __restrict__ inv1, const float* __restrict__ Wup1,
                     const int* __restrict__ cnt_in, const int* __restrict__ selfc,
                     float* __restrict__ Yfsc) {
  __shared__ float red[3][HID];
  int i = blockIdx.x, t = threadIdx.x;
  float v = h0[i * HID + t];
  int ii = inv1[i];
  if (ii >= 0 && ii < K1N) v += u1b[ii * HID + t];
#pragma unroll
  for (int c = 0; c < 3; ++c) red[c][t] = v * Wup1[t * 3 + c];
  __syncthreads();
  for (int s = 64; s > 0; s >>= 1) {
    if (t < s) { red[0][t] += red[0][t + s]; red[1][t] += red[1][t + s]; red[2][t] += red[2][t + s]; }
    __syncthreads();
  }
  if (t < 3) {
    float d0 = 1.0f / sqrtf((float)(cnt_in[i] + selfc[i] + 2));
    Yfsc[i * 3 + t] = d0 * red[t][0];
  }
}

__global__ void k_final(const float* __restrict__ Yfsc, const int* __restrict__ cnt_in,
                        const int* __restrict__ col_in, const int* __restrict__ selfc,
                        const float* __restrict__ bup1, const float* __restrict__ z,
                        float* __restrict__ out) {
  int idx = blockIdx.x * blockDim.x + threadIdx.x;
  if (idx >= N0 * 3) return;
  int d = idx / 3, c = idx - d * 3;
  int cntu = cnt_in[d];
  int cnt = cntu > CAP ? CAP : cntu;
  float acc = (2.0f + (float)selfc[d]) * Yfsc[d * 3 + c];
  int e = 0;
  for (; e + 8 <= cnt; e += 8) {
    float y[8];
#pragma unroll
    for (int j = 0; j < 8; ++j) y[j] = Yfsc[col_in[d * CAP + e + j] * 3 + c];
#pragma unroll
    for (int j = 0; j < 8; ++j) acc += y[j];
  }
  for (; e < cnt; ++e) acc += Yfsc[col_in[d * CAP + e] * 3 + c];
  float d0 = 1.0f / sqrtf((float)(cntu + selfc[d] + 2));
  out[idx] = d0 * acc + bup1[c] + 0.1f * z[idx];
}

// ======================================================================
// =====================  COOPERATIVE MEGA-KERNEL  ======================
// ======================================================================

union SMem {
  struct {
    unsigned setA[N0]; unsigned setB[N0];
    int hist[256]; int sscan[257];
    unsigned pfx; int rem; int cnt;
    int cgt[48], ceq[48], bgt[48], beq[48];
  } tk;                                                   // ~26.8 KB
  struct { float Wt[32 * HID]; float Xt[32 * ATS]; } yw;  // 21 KB
  struct { float red[8][HID]; float red2[8][HID]; } gcn;  // 8 KB
  struct { int outl[8][CAP]; int inl[8][CAP]; int invo[8][CAP]; int invi[8][CAP]; } pr; // 16 KB
  struct { int cntw[8][2]; float wsum[8][2]; } csr;       // tiny
  struct { int q[K2N]; } cmp;                             // 3 KB
  struct { float wred[4][4]; } sq;                        // tiny
  struct { int klist[8][768]; float wlist[8][768]; int cntw[8][2];
           float red[8][HID]; float red2[8][HID]; } sp;   // ~57.4 KB (max)
  struct { float red[8][3][HID]; } yf;                    // 12 KB
};

struct MP {
  const float *x, *z, *Wd0, *bd0, *Wd1, *bd1, *Wd2, *bd2, *p1, *p2, *Wu0, *bu0, *Wu1, *bu1;
  const int* ei;
  float* A1; short* Ac; float* A2; float* Ysc; float *h0, *h1, *h2, *u1b, *Yfsc;
  float *score, *gate1, *gate2, *dis1, *dis2;
  int *perm1, *perm2, *inv1, *inv2, *cnt_in, *cnt_out, *selfc, *col_in, *col_out;
  int *csr_n, *csr_k; float* csr_w;
  float* outv; float* outlab;
};

// ---- stage: dense tile GEMM Ysc = scale * (X[perm] (+X2 scatter)) @ W ----
__device__ __forceinline__ void st_yw2(SMem* sm, const float* X, const float* X2,
                                       const int* inv2c, int Kin, int nsrc, int n,
                                       const float* Wm, const int* perm,
                                       const float* gate, const float* dis,
                                       const int* cntd, const int* selfd, float* Ysc) {
  int t = threadIdx.x;
  int ntiles = (n + BM - 1) / BM;
  for (int tile = blockIdx.x; tile < ntiles; tile += GRD) {
    int r0 = tile * BM;
    bool act = (t < 256);
    int f4 = (t & 31) * 4;
    int rg = (t >> 5) & 7;
    float4 acc0 = {0,0,0,0}, acc1 = {0,0,0,0}, acc2 = {0,0,0,0}, acc3 = {0,0,0,0};
    for (int kb = 0; kb < Kin; kb += 32) {
      if (act) {
        const float4* src = (const float4*)(Wm + (size_t)kb * HID);
        float4* dst = (float4*)sm->yw.Wt;
#pragma unroll
        for (int i = 0; i < 4; ++i) dst[i * 256 + t] = src[i * 256 + t];
        int j = t >> 3;
        int k4 = (t & 7) * 4;
        int r = r0 + j;
        int src_row = (r < n) ? r : (n - 1);
        if (perm) {
          int s = perm[src_row];
          if (s < 0) s = 0;
          if (s >= nsrc) s = nsrc - 1;
          src_row = s;
        }
        float4 xv = *(const float4*)(X + (size_t)src_row * Kin + kb + k4);
        if (X2) {
          int ii = inv2c[src_row];
          if (ii >= 0 && ii < K2N) {
            float4 x2 = *(const float4*)(X2 + (size_t)ii * Kin + kb + k4);
            xv.x += x2.x; xv.y += x2.y; xv.z += x2.z; xv.w += x2.w;
          }
        }
        sm->yw.Xt[(k4 + 0) * ATS + j] = xv.x;
        sm->yw.Xt[(k4 + 1) * ATS + j] = xv.y;
        sm->yw.Xt[(k4 + 2) * ATS + j] = xv.z;
        sm->yw.Xt[(k4 + 3) * ATS + j] = xv.w;
      }
      __syncthreads();
      if (act) {
#pragma unroll 4
        for (int kk = 0; kk < 32; ++kk) {
          float4 y = *(const float4*)&sm->yw.Wt[kk * HID + f4];
          float4 a = *(const float4*)&sm->yw.Xt[kk * ATS + rg * 4];
          acc0.x += a.x * y.x; acc0.y += a.x * y.y; acc0.z += a.x * y.z; acc0.w += a.x * y.w;
          acc1.x += a.y * y.x; acc1.y += a.y * y.y; acc1.z += a.y * y.z; acc1.w += a.y * y.w;
          acc2.x += a.z * y.x; acc2.y += a.z * y.y; acc2.z += a.z * y.z; acc2.w += a.z * y.w;
          acc3.x += a.w * y.x; acc3.y += a.w * y.y; acc3.z += a.w * y.z; acc3.w += a.w * y.w;
        }
      }
      __syncthreads();
    }
    if (act) {
      int r = r0 + rg * 4;
      float4* accs[4] = {&acc0, &acc1, &acc2, &acc3};
#pragma unroll
      for (int j = 0; j < 4; ++j) {
        int row = r + j;
        if (row >= n) continue;
        float g = gate ? gate[row] : 1.0f;
        float d = dis ? dis[row] : (1.0f / sqrtf((float)(cntd[row] + selfd[row] + 2)));
        float s = d * g;
        float4 a = *accs[j];
        *(float4*)&Ysc[(size_t)row * HID + f4] = make_float4(s * a.x, s * a.y, s * a.z, s * a.w);
      }
    }
  }
}

// ---- stage: CSR spmv + epilogue (+ optional fused score); 8 subs x 128 ----
__device__ __forceinline__ void st_spmv_csr(SMem* sm, const int* csr_n, const int* csr_k,
                                            const float* csr_w, const float* Ysc,
                                            const float* dis, const float* bias,
                                            const float* pvec, float* H, float* score,
                                            int act) {
  int t = threadIdx.x, sub = t >> 7, tl = t & 127;
  int r = blockIdx.x * 8 + sub;        // K1N <= GRD*8, single pass
  bool ok = (r < K1N);
  int rr = ok ? r : 0;
  int nnz = ok ? csr_n[rr] : 0;
  const int* gk = csr_k + (size_t)rr * RCAP;
  const float* gw = csr_w + (size_t)rr * RCAP;
  float acc = 0.0f;
  int pp = 0;
  for (; pp + 8 <= nnz; pp += 8) {
    int kk[8]; float ww[8]; float y[8];
#pragma unroll
    for (int j = 0; j < 8; ++j) { kk[j] = gk[pp + j]; ww[j] = gw[pp + j]; }
#pragma unroll
    for (int j = 0; j < 8; ++j) y[j] = Ysc[(size_t)kk[j] * HID + tl];
#pragma unroll
    for (int j = 0; j < 8; ++j) acc += ww[j] * y[j];
  }
  for (; pp < nnz; ++pp) acc += gw[pp] * Ysc[(size_t)gk[pp] * HID + tl];
  float h = 0.0f;
  if (ok) {
    float zv = dis[rr] * (acc + 2.0f * Ysc[(size_t)rr * HID + tl]) + bias[tl];
    h = act ? tanhf(zv) : zv;
    H[(size_t)rr * HID + tl] = h;
  }
  if (pvec) {
    float pv = pvec[tl];
    sm->gcn.red[sub][tl] = h * pv;
    sm->gcn.red2[sub][tl] = pv * pv;
    __syncthreads();
    for (int s = 64; s > 0; s >>= 1) {
      if (tl < s) {
        sm->gcn.red[sub][tl] += sm->gcn.red[sub][tl + s];
        sm->gcn.red2[sub][tl] += sm->gcn.red2[sub][tl + s];
      }
      __syncthreads();
    }
    if (ok && tl == 0)
      score[rr] = tanhf(sm->gcn.red[sub][0] * (1.0f / sqrtf(sm->gcn.red2[sub][0])));
  }
}

// ---- stage: top-K (block 0 only, full 1024 threads, verbatim port) ----
__device__ void st_topk(SMem* sm, const float* score, int n, int K,
                        int* perm, float* gatec, int* inv) {
  if (blockIdx.x != 0) return;
  int t = threadIdx.x;
  int lane = t & 63, wv = t >> 6;
  unsigned long long below = (lane == 0) ? 0ull : (~0ull >> (64 - lane));
  unsigned* setA = sm->tk.setA;
  unsigned* setB = sm->tk.setB;
  int* hist = sm->tk.hist;
  int* sscan = sm->tk.sscan;
  for (int i = t; i < n; i += MBT) setA[i] = fkey(score[i]);
  __syncthreads();
  unsigned prefix = 0; int rem = K; int m = n;
  unsigned* cur = setA; unsigned* nxt = setB;
  for (int pass = 3; pass >= 0; --pass) {
    if (t < 256) hist[t] = 0;
    __syncthreads();
    for (int i = t; i < m; i += MBT) atomicAdd(&hist[(cur[i] >> (pass * 8)) & 255], 1);
    __syncthreads();
    if (t < 256) { sscan[t] = hist[t]; if (t == 0) sscan[256] = 0; }
    __syncthreads();
    for (int off = 1; off < 256; off <<= 1) {
      int add = 0;
      if (t < 256) add = (t + off < 256) ? sscan[t + off] : 0;
      __syncthreads();
      if (t < 256) sscan[t] += add;
      __syncthreads();
    }
    if (t < 256 && sscan[t] >= rem && sscan[t + 1] < rem) {
      sm->tk.pfx = prefix | ((unsigned)t << (pass * 8));
      sm->tk.rem = rem - sscan[t + 1];
    }
    __syncthreads();
    prefix = sm->tk.pfx; rem = sm->tk.rem;
    if (pass > 0) {
      unsigned dg = (prefix >> (pass * 8)) & 255u;
      if (t == 0) sm->tk.cnt = 0;
      __syncthreads();
      for (int c0 = 0; c0 < m; c0 += MBT) {
        int i = c0 + t;
        unsigned u = (i < m) ? cur[i] : 0u;
        bool match = (i < m) && (((u >> (pass * 8)) & 255u) == dg);
        unsigned long long mm = __ballot(match);
        int cw = (int)__popcll(mm);
        int basew = 0;
        if (lane == 0 && cw) basew = atomicAdd(&sm->tk.cnt, cw);
        basew = __shfl(basew, 0);
        if (match) nxt[basew + (int)__popcll(mm & below)] = u;
      }
      __syncthreads();
      m = sm->tk.cnt;
      unsigned* tmp = cur; cur = nxt; nxt = tmp;
    }
  }
  unsigned uthr = prefix;
  int c_gt = K - rem;
  int NC = (n + 63) >> 6;
  for (int c = wv; c < NC; c += 16) {
    int i = (c << 6) + lane;
    unsigned u = (i < n) ? fkey(score[i]) : 0u;
    bool isgt = (i < n) && (u > uthr);
    bool iseq = (i < n) && (u == uthr);
    unsigned long long mg = __ballot(isgt);
    unsigned long long me = __ballot(iseq);
    if (lane == 0) { sm->tk.cgt[c] = (int)__popcll(mg); sm->tk.ceq[c] = (int)__popcll(me); }
  }
  __syncthreads();
  if (t == 0) {
    int g = 0, e = 0;
    for (int c = 0; c < NC; ++c) {
      sm->tk.bgt[c] = g; g += sm->tk.cgt[c];
      sm->tk.beq[c] = e; e += sm->tk.ceq[c];
    }
  }
  __syncthreads();
  for (int c = wv; c < NC; c += 16) {
    int i = (c << 6) + lane;
    unsigned u = (i < n) ? fkey(score[i]) : 0u;
    bool isgt = (i < n) && (u > uthr);
    bool iseq = (i < n) && (u == uthr);
    unsigned long long mg = __ballot(isgt);
    unsigned long long me = __ballot(iseq);
    if (isgt) {
      int pos = sm->tk.bgt[c] + (int)__popcll(mg & below);
      perm[pos] = i; gatec[pos] = inv_fkey(u); inv[i] = pos;
    } else if (iseq) {
      int er = sm->tk.beq[c] + (int)__popcll(me & below);
      if (er < rem) { int pos = c_gt + er; perm[pos] = i; gatec[pos] = inv_fkey(u); inv[i] = pos; }
    }
  }
}

__global__ __launch_bounds__(MBT) void mega(MP p) {
  cg::grid_group grid = cg::this_grid();
  __shared__ SMem sm;
  const int t = threadIdx.x;
  const int b = blockIdx.x;

  // ---- S0: init fills ----
  {
    int i = b * MBT + t, st = GRD * MBT;
    for (int j = i; j < K1N * LD1; j += st) p.A1[j] = 0.0f;
    for (int j = i; j < K1N + K2N; j += st) p.gate1[j] = 0.0f;
    for (int j = i; j < K1N + K2N; j += st) p.perm1[j] = 0;
    for (int j = i; j < N0 + K1N; j += st) p.inv1[j] = -1;
    for (int j = i; j < 3 * N0; j += st) p.cnt_in[j] = 0;
    for (int j = i; j < N0 * 29; j += st) p.outlab[j] = 0.0f;
  }
  grid.sync();

  // ---- S1: edge lists ----
  {
    for (int e = b * MBT + t; e < E0; e += GRD * MBT) {
      int s = p.ei[e], d = p.ei[E0 + e];
      if (s == d) { atomicAdd(&p.selfc[d], 1); continue; }
      int a = atomicAdd(&p.cnt_in[d], 1);
      if (a < CAP) p.col_in[d * CAP + a] = s;
      int bb = atomicAdd(&p.cnt_out[s], 1);
      if (bb < CAP) p.col_out[s * CAP + bb] = d;
    }
  }
  grid.sync();

  // ---- S2: level-0 YW ----
  st_yw2(&sm, p.x, nullptr, nullptr, 32, N0, N0, p.Wd0, nullptr, nullptr, nullptr,
         p.cnt_in, p.selfc, p.Ysc);
  grid.sync();

  // ---- S3: level-0 sparse GCN + score (8 subs x 128, 2 passes) ----
  {
    int sub = t >> 7, f = t & 127;
    for (int it = 0; it < 2; ++it) {
      int d = it * (GRD * 8) + b * 8 + sub;
      bool ok = (d < N0);
      int dd = ok ? d : 0;
      int cntu = p.cnt_in[dd];
      int cnt = cntu > CAP ? CAP : cntu;
      float acc = (2.0f + (float)p.selfc[dd]) * p.Ysc[dd * HID + f];
      int e = 0;
      for (; e + 8 <= cnt; e += 8) {
        float y[8];
#pragma unroll
        for (int j = 0; j < 8; ++j) y[j] = p.Ysc[p.col_in[dd * CAP + e + j] * HID + f];
#pragma unroll
        for (int j = 0; j < 8; ++j) acc += y[j];
      }
      for (; e < cnt; ++e) acc += p.Ysc[p.col_in[dd * CAP + e] * HID + f];
      float d0 = 1.0f / sqrtf((float)(cntu + p.selfc[dd] + 2));
      float h = tanhf(d0 * acc + p.bd0[f]);
      if (ok) p.h0[dd * HID + f] = h;
      float pv = p.p1[f];
      sm.gcn.red[sub][f] = h * pv;
      sm.gcn.red2[sub][f] = pv * pv;
      __syncthreads();
      for (int s = 64; s > 0; s >>= 1) {
        if (f < s) {
          sm.gcn.red[sub][f] += sm.gcn.red[sub][f + s];
          sm.gcn.red2[sub][f] += sm.gcn.red2[sub][f + s];
        }
        __syncthreads();
      }
      if (ok && f == 0)
        p.score[dd] = tanhf(sm.gcn.red[sub][0] * (1.0f / sqrtf(sm.gcn.red2[sub][0])));
      __syncthreads();
    }
  }
  grid.sync();

  // ---- S4: top-K #1 ----
  st_topk(&sm, p.score, N0, K1N, p.perm1, p.gate1, p.inv1);
  grid.sync();

  // ---- S5: A1 pair scatter (8 subs x 128, 2 passes) ----
  {
    int sub = t >> 7, tl = t & 127;
    for (int it = 0; it < 2; ++it) {
      int k = it * (GRD * 8) + b * 8 + sub;
      bool ok = (k < N0);
      int kk = ok ? k : 0;
      int no = p.cnt_out[kk]; if (no > CAP) no = CAP;
      int ni = p.cnt_in[kk];  if (ni > CAP) ni = CAP;
      if (!ok) { no = 0; ni = 0; }
      if (tl < no) { int i = p.col_out[kk * CAP + tl]; sm.pr.outl[sub][tl] = i; sm.pr.invo[sub][tl] = p.inv1[i]; }
      if (tl < ni) { int j = p.col_in[kk * CAP + tl];  sm.pr.inl[sub][tl] = j;  sm.pr.invi[sub][tl] = p.inv1[j]; }
      __syncthreads();
      int invk = p.inv1[kk];
      if (tl < ni && invk >= 0) {
        int jj = sm.pr.invi[sub][tl];
        if (jj >= 0) atomicAdd(&p.A1[(size_t)invk * LD1 + jj], 2.0f);
      }
      for (int a = tl; a < no; a += 128) {
        int i = sm.pr.outl[sub][a], ii = sm.pr.invo[sub][a];
        if (ii < 0) continue;
        for (int bb = 0; bb < ni; ++bb) {
          int jj = sm.pr.invi[sub][bb];
          if (jj >= 0 && i != sm.pr.inl[sub][bb]) atomicAdd(&p.A1[(size_t)ii * LD1 + jj], 1.0f);
        }
      }
      __syncthreads();
    }
  }
  grid.sync();

  // ---- S6: A1 CSR + dis1 (8 subs x 128, single pass) ----
  {
    int sub = t >> 7, tl = t & 127;
    int r = b * 8 + sub;
    bool ok = (r < K1N);
    int rr = ok ? r : 0;
    const float* arow = p.A1 + (size_t)rr * LD1;
    int wid = tl >> 6, lane = tl & 63;
    unsigned long long below = (lane == 0) ? 0ull : (~0ull >> (64 - lane));
    int base = 0;
    float wsum = 0.0f;
    int* gk = p.csr_k + (size_t)rr * RCAP;
    float* gw = p.csr_w + (size_t)rr * RCAP;
    for (int c0 = 0; c0 < K1N; c0 += 128) {
      int col = c0 + tl;
      float w = (ok && col < K1N) ? arow[col] : 0.0f;
      wsum += w;
      bool nz = (w != 0.0f);
      unsigned long long m = __ballot(nz);
      if (lane == 0) sm.csr.cntw[sub][wid] = (int)__popcll(m);
      __syncthreads();
      int pos = base + (wid ? sm.csr.cntw[sub][0] : 0) + (int)__popcll(m & below);
      if (nz) { gk[pos] = col; gw[pos] = w; }
      base += sm.csr.cntw[sub][0] + sm.csr.cntw[sub][1];
      __syncthreads();
    }
    for (int off = 32; off > 0; off >>= 1) wsum += __shfl_down(wsum, off);
    if (lane == 0) sm.csr.wsum[sub][wid] = wsum;
    __syncthreads();
    if (ok && tl == 0) {
      p.csr_n[rr] = base;
      p.dis1[rr] = 1.0f / sqrtf(sm.csr.wsum[sub][0] + sm.csr.wsum[sub][1] + 2.0f);
    }
  }
  grid.sync();

  // ---- S7: level-1 YW ----
  st_yw2(&sm, p.h0, nullptr, nullptr, HID, N0, K1N, p.Wd1, p.perm1, p.gate1, p.dis1,
         nullptr, nullptr, p.Ysc);
  grid.sync();

  // ---- S8: level-1 CSR spmv + score ----
  st_spmv_csr(&sm, p.csr_n, p.csr_k, p.csr_w, p.Ysc, p.dis1, p.bd1, p.p2, p.h1, p.score, 1);
  grid.sync();

  // ---- S9: top-K #2 ----
  st_topk(&sm, p.score, K1N, K2N, p.perm2, p.gate2, p.inv2);
  grid.sync();

  // ---- S10: column compaction Ac (4 subs x 256, 2 passes; shared q) ----
  {
    for (int i = t; i < K2N; i += MBT) {
      int v = p.perm2[i];
      if (v < 0) v = 0;
      if (v >= K1N) v = K1N - 1;
      sm.cmp.q[i] = v;
    }
    __syncthreads();
    int sub = t >> 8, tl = t & 255;
    for (int it = 0; it < 2; ++it) {
      int k = it * (GRD * 4) + b * 4 + sub;
      if (k < K1N) {
        const float* row = p.A1 + (size_t)k * LD1;
        short* dst = p.Ac + (size_t)k * LD2;
        for (int bb = tl; bb < LD2; bb += 256) dst[bb] = (bb < K2N) ? (short)row[sm.cmp.q[bb]] : (short)0;
      }
    }
  }
  grid.sync();

  // ---- S11: A2 + dis2 (4 subs x 256 (192 active), single pass) ----
  {
    int sub = t >> 8, tl = t & 255;
    int a = b * 4 + sub;
    bool ok = (a < K2N);
    int aa = ok ? a : 0;
    int qa = p.perm2[aa];
    if (qa < 0) qa = 0;
    if (qa >= K1N) qa = K1N - 1;
    const float* arow = p.A1 + (size_t)qa * LD1;
    int nnz = ok ? p.csr_n[qa] : 0;
    const int* gk = p.csr_k + (size_t)qa * RCAP;
    const float* gw = p.csr_w + (size_t)qa * RCAP;
    bool active = ok && (tl < 192);
    int c0 = tl * 4;
    float4 acc = make_float4(0.f, 0.f, 0.f, 0.f);
    int pp = 0;
    for (; pp + 8 <= nnz; pp += 8) {
      int kk[8]; float ww[8];
#pragma unroll
      for (int j = 0; j < 8; ++j) { kk[j] = gk[pp + j]; ww[j] = gw[pp + j]; }
      if (active) {
        short4 v[8];
#pragma unroll
        for (int j = 0; j < 8; ++j) v[j] = *(const short4*)&p.Ac[(size_t)kk[j] * LD2 + c0];
#pragma unroll
        for (int j = 0; j < 8; ++j) {
          acc.x += ww[j] * (float)v[j].x;
          acc.y += ww[j] * (float)v[j].y;
          acc.z += ww[j] * (float)v[j].z;
          acc.w += ww[j] * (float)v[j].w;
        }
      }
    }
    for (; pp < nnz; ++pp) {
      int k2 = gk[pp]; float w = gw[pp];
      if (active) {
        short4 v = *(const short4*)&p.Ac[(size_t)k2 * LD2 + c0];
        acc.x += w * (float)v.x; acc.y += w * (float)v.y;
        acc.z += w * (float)v.z; acc.w += w * (float)v.w;
      }
    }
    float rsum = 0.0f;
    if (active) {
      float accv[4] = {acc.x, acc.y, acc.z, acc.w};
      float outv[4];
#pragma unroll
      for (int j = 0; j < 4; ++j) {
        int col = c0 + j;
        float v = 0.0f;
        if (col < K2N && col != aa) {
          int qb = p.perm2[col];
          if (qb < 0) qb = 0;
          if (qb >= K1N) qb = K1N - 1;
          v = accv[j] + 2.0f * arow[qb];
        }
        outv[j] = v;
        rsum += v;
      }
      *(float4*)&p.A2[(size_t)aa * LD2 + c0] = make_float4(outv[0], outv[1], outv[2], outv[3]);
    }
    for (int off = 32; off > 0; off >>= 1) rsum += __shfl_down(rsum, off);
    if ((tl & 63) == 0) sm.sq.wred[sub][tl >> 6] = rsum;
    __syncthreads();
    if (ok && tl == 0)
      p.dis2[aa] = 1.0f / sqrtf(sm.sq.wred[sub][0] + sm.sq.wred[sub][1] + sm.sq.wred[sub][2] + 2.0f);
  }
  grid.sync();

  // ---- S12: level-2 YW ----
  st_yw2(&sm, p.h1, nullptr, nullptr, HID, K1N, K2N, p.Wd2, p.perm2, p.gate2, p.dis2,
         nullptr, nullptr, p.Ysc);
  grid.sync();

  // ---- S13: level-2 dense-scan spmv on A2 (8 subs x 128, single pass) ----
  {
    int sub = t >> 7, tl = t & 127;
    int r = b * 8 + sub;
    bool ok = (r < K2N);
    int rr = ok ? r : 0;
    const float* arow = p.A2 + (size_t)rr * LD2;
    int wid = tl >> 6, lane = tl & 63;
    unsigned long long below = (lane == 0) ? 0ull : (~0ull >> (64 - lane));
    int base = 0;
    for (int c0 = 0; c0 < K2N; c0 += 128) {
      int col = c0 + tl;
      float w = (ok && col < K2N) ? arow[col] : 0.0f;
      bool nz = (w != 0.0f);
      unsigned long long m = __ballot(nz);
      if (lane == 0) sm.sp.cntw[sub][wid] = (int)__popcll(m);
      __syncthreads();
      int pos = base + (wid ? sm.sp.cntw[sub][0] : 0) + (int)__popcll(m & below);
      if (nz) { sm.sp.klist[sub][pos] = col; sm.sp.wlist[sub][pos] = w; }
      base += sm.sp.cntw[sub][0] + sm.sp.cntw[sub][1];
      __syncthreads();
    }
    int nnz = base;
    float acc = 0.0f;
    int pp = 0;
    for (; pp + 8 <= nnz; pp += 8) {
      float y[8];
#pragma unroll
      for (int j = 0; j < 8; ++j) y[j] = p.Ysc[(size_t)sm.sp.klist[sub][pp + j] * HID + tl];
#pragma unroll
      for (int j = 0; j < 8; ++j) acc += sm.sp.wlist[sub][pp + j] * y[j];
    }
    for (; pp < nnz; ++pp) acc += sm.sp.wlist[sub][pp] * p.Ysc[(size_t)sm.sp.klist[sub][pp] * HID + tl];
    if (ok) {
      float zv = p.dis2[rr] * (acc + 2.0f * p.Ysc[(size_t)rr * HID + tl]) + p.bd2[tl];
      p.h2[(size_t)rr * HID + tl] = tanhf(zv);
    }
  }
  grid.sync();

  // ---- S14: up-path YW (combine h1 + scatter(h2)) ----
  st_yw2(&sm, p.h1, p.h2, p.inv2, HID, K1N, K1N, p.Wu0, nullptr, nullptr, p.dis1,
         nullptr, nullptr, p.Ysc);
  grid.sync();

  // ---- S15: up-path CSR spmv ----
  st_spmv_csr(&sm, p.csr_n, p.csr_k, p.csr_w, p.Ysc, p.dis1, p.bu0, nullptr, p.u1b, nullptr, 1);
  grid.sync();

  // ---- S16: Yf (8 subs x 128, 2 passes) ----
  {
    int sub = t >> 7, tl = t & 127;
    for (int it = 0; it < 2; ++it) {
      int i = it * (GRD * 8) + b * 8 + sub;
      bool ok = (i < N0);
      int i0 = ok ? i : 0;
      float v = p.h0[(size_t)i0 * HID + tl];
      int ii = p.inv1[i0];
      if (ii >= 0 && ii < K1N) v += p.u1b[(size_t)ii * HID + tl];
#pragma unroll
      for (int c = 0; c < 3; ++c) sm.yf.red[sub][c][tl] = v * p.Wu1[tl * 3 + c];
      __syncthreads();
      for (int s = 64; s > 0; s >>= 1) {
        if (tl < s) {
          sm.yf.red[sub][0][tl] += sm.yf.red[sub][0][tl + s];
          sm.yf.red[sub][1][tl] += sm.yf.red[sub][1][tl + s];
          sm.yf.red[sub][2][tl] += sm.yf.red[sub][2][tl + s];
        }
        __syncthreads();
      }
      if (ok && tl < 3) {
        float d0 = 1.0f / sqrtf((float)(p.cnt_in[i0] + p.selfc[i0] + 2));
        p.Yfsc[i0 * 3 + tl] = d0 * sm.yf.red[sub][tl][0];
      }
      __syncthreads();
    }
  }
  grid.sync();

  // ---- S17: final ----
  {
    for (int idx = b * MBT + t; idx < N0 * 3; idx += GRD * MBT) {
      int d = idx / 3, c = idx - d * 3;
      int cntu = p.cnt_in[d];
      int cnt = cntu > CAP ? CAP : cntu;
      float acc = (2.0f + (float)p.selfc[d]) * p.Yfsc[d * 3 + c];
      int e = 0;
      for (; e + 8 <= cnt; e += 8) {
        float y[8];
#pragma unroll
        for (int j = 0; j < 8; ++j) y[j] = p.Yfsc[p.col_in[d * CAP + e + j] * 3 + c];
#pragma unroll
        for (int j = 0; j < 8; ++j) acc += y[j];
      }
      for (; e < cnt; ++e) acc += p.Yfsc[p.col_in[d * CAP + e] * 3 + c];
      float d0 = 1.0f / sqrtf((float)(cntu + p.selfc[d] + 2));
      p.outv[idx] = d0 * acc + p.bu1[c] + 0.1f * p.z[idx];
    }
  }
}

// ======================================================================

extern "C" void kernel_launch(void* const* d_in, const int* in_sizes, int n_in,
                              void* d_out, int out_size, void* d_ws, size_t ws_size,
                              hipStream_t stream) {
  const float* x   = (const float*)d_in[0];
  const float* z   = (const float*)d_in[1];
  const float* Wd0 = (const float*)d_in[2];
  const float* bd0 = (const float*)d_in[3];
  const float* Wd1 = (const float*)d_in[4];
  const float* bd1 = (const float*)d_in[5];
  const float* Wd2 = (const float*)d_in[6];
  const float* bd2 = (const float*)d_in[7];
  const float* p1  = (const float*)d_in[8];
  const float* p2  = (const float*)d_in[9];
  const float* Wu0 = (const float*)d_in[10];
  const float* bu0 = (const float*)d_in[11];
  const float* Wu1 = (const float*)d_in[12];
  const float* bu1 = (const float*)d_in[13];
  const int*   ei  = (const int*)d_in[14];

  if (ws_size < F_END * sizeof(float)) return;

  float* W     = (float*)d_ws;
  float* A1    = W + F_A1;
  short* Ac    = (short*)(W + F_SCR);
  float* A2    = W + F_A2;
  float* Ysc   = W + F_YSC;
  float* h0    = W + F_H0;
  float* h1    = W + F_H1;
  float* h2    = W + F_H2;
  float* u1b   = W + F_U1B;
  float* Yfsc  = W + F_YF;
  float* score = W + F_SCORE;
  float* gate1 = W + F_GATE1;
  float* gate2 = W + F_GATE2;
  float* dis1  = W + F_DIS1;
  float* dis2  = W + F_DIS2;
  int* perm1   = (int*)(W + F_PERM1);
  int* perm2   = (int*)(W + F_PERM2);
  int* inv1    = (int*)(W + F_INV1);
  int* inv2    = (int*)(W + F_INV2);
  int* cnt_in  = (int*)(W + F_CNTI);
  int* cnt_out = (int*)(W + F_CNTO);
  int* selfc   = (int*)(W + F_SELF);
  int* col_in  = (int*)(W + F_CI);
  int* col_out = (int*)(W + F_CO);
  int* csr_n   = (int*)(W + F_CSRN);
  int* csr_k   = (int*)(W + F_CSRK);
  float* csr_w = W + F_CSRW;
  float* out   = (float*)d_out;

  // ---- try the cooperative mega-kernel (1 dispatch, 17 grid syncs) ----
  MP prm;
  prm.x = x; prm.z = z; prm.Wd0 = Wd0; prm.bd0 = bd0; prm.Wd1 = Wd1; prm.bd1 = bd1;
  prm.Wd2 = Wd2; prm.bd2 = bd2; prm.p1 = p1; prm.p2 = p2; prm.Wu0 = Wu0; prm.bu0 = bu0;
  prm.Wu1 = Wu1; prm.bu1 = bu1; prm.ei = ei;
  prm.A1 = A1; prm.Ac = Ac; prm.A2 = A2; prm.Ysc = Ysc; prm.h0 = h0; prm.h1 = h1;
  prm.h2 = h2; prm.u1b = u1b; prm.Yfsc = Yfsc; prm.score = score;
  prm.gate1 = gate1; prm.gate2 = gate2; prm.dis1 = dis1; prm.dis2 = dis2;
  prm.perm1 = perm1; prm.perm2 = perm2; prm.inv1 = inv1; prm.inv2 = inv2;
  prm.cnt_in = cnt_in; prm.cnt_out = cnt_out; prm.selfc = selfc;
  prm.col_in = col_in; prm.col_out = col_out;
  prm.csr_n = csr_n; prm.csr_k = csr_k; prm.csr_w = csr_w;
  prm.outv = out; prm.outlab = out + N0 * 3;
  void* kargs[] = { (void*)&prm };
  hipError_t err = hipLaunchCooperativeKernel((const void*)mega, dim3(GRD), dim3(MBT),
                                              kargs, 0, stream);
  if (err == hipSuccess) return;
  (void)hipGetLastError();  // clear error state, fall back to multi-kernel path

  // ---- fallback: round-1 verified 18-dispatch pipeline ----
  k_init<<<1024, 256, 0, stream>>>(A1, gate1, perm1, inv1, cnt_in, out + N0 * 3);
  k_count<<<(E0 + 255) / 256, 256, 0, stream>>>(ei, cnt_in, cnt_out, selfc, col_in, col_out);
  k_yw2<<<(N0 + BM - 1) / BM, 256, 0, stream>>>(x, nullptr, nullptr, 32, N0, N0, Wd0,
                                                nullptr, nullptr, nullptr, cnt_in, selfc, Ysc);
  k_gcn_sparse<<<N0, HID, 0, stream>>>(Ysc, cnt_in, col_in, selfc, bd0, p1, h0, score);
  k_topk<<<1, TKT, 0, stream>>>(score, N0, K1N, perm1, gate1, inv1);
  k_pairs<<<N0, 128, 0, stream>>>(cnt_in, col_in, cnt_out, col_out, inv1, A1);
  k_a1csr<<<K1N, 128, 0, stream>>>(A1, csr_n, csr_k, csr_w, dis1);
  k_yw2<<<(K1N + BM - 1) / BM, 256, 0, stream>>>(h0, nullptr, nullptr, HID, N0, K1N, Wd1,
                                                 perm1, gate1, dis1, nullptr, nullptr, Ysc);
  k_spmv_csr<<<K1N, 128, 0, stream>>>(csr_n, csr_k, csr_w, Ysc, dis1, bd1, p2, h1, score, 1);
  k_topk<<<1, TKT, 0, stream>>>(score, K1N, K2N, perm2, gate2, inv2);
  k_cmp<<<K1N, 256, 0, stream>>>(A1, perm2, Ac);
  k_sq2<<<K2N, 192, 0, stream>>>(A1, Ac, perm2, csr_n, csr_k, csr_w, A2, dis2);
  k_yw2<<<(K2N + BM - 1) / BM, 256, 0, stream>>>(h1, nullptr, nullptr, HID, K1N, K2N, Wd2,
                                                 perm2, gate2, dis2, nullptr, nullptr, Ysc);
  k_spmv<<<K2N, 128, 0, stream>>>(A2, K2N, LD2, Ysc, dis2, bd2, nullptr, h2, nullptr, 1);
  k_yw2<<<(K1N + BM - 1) / BM, 256, 0, stream>>>(h1, h2, inv2, HID, K1N, K1N, Wu0,
                                                 nullptr, nullptr, dis1, nullptr, nullptr, Ysc);
  k_spmv_csr<<<K1N, 128, 0, stream>>>(csr_n, csr_k, csr_w, Ysc, dis1, bu0, nullptr, u1b, nullptr, 1);
  k_yf<<<N0, HID, 0, stream>>>(h0, u1b, inv1, Wu1, cnt_in, selfc, Yfsc);
  k_final<<<(N0 * 3 + 255) / 256, 256, 0, stream>>>(Yfsc, cnt_in, col_in, selfc, bu1, z, out);
}

// Round 3
// 250.463 us; speedup vs baseline: 3.1769x; 3.1769x over previous
//
#include <hip/hip_runtime.h>
#include <hip/hip_bf16.h>

#define N0   3000
#define E0   48000
#define K1N  1500
#define K2N  750
#define HID  128
#define CAP  128
#define LD1  1536  // padded leading dim for A1
#define LD2  768   // padded leading dim for A2/Ac
#define BM   32    // row-tile for k_yw2
#define ATS  36    // transposed X-tile stride (BM+4, bank-spread)
#define RCAP 1536  // CSR row capacity (>= max possible nnz = K1N)
#define TKT  1024  // k_topk threads (16 waves on one CU)

__device__ __forceinline__ unsigned fkey(float f) {
  unsigned u = __float_as_uint(f);
  return (u & 0x80000000u) ? ~u : (u | 0x80000000u);
}
__device__ __forceinline__ float inv_fkey(unsigned u) {
  unsigned v = (u & 0x80000000u) ? (u & 0x7FFFFFFFu) : ~u;
  return __uint_as_float(v);
}

// ---------------- workspace layout (float units) ----------------
constexpr size_t F_A1    = 0;                          // K1N*LD1
constexpr size_t F_SCR   = F_A1 + (size_t)K1N * LD1;   // Ac (int16) = K1N*LD2 shorts
constexpr size_t SCR_SZ  = 1155072;                    // plenty
constexpr size_t F_A2    = F_SCR + SCR_SZ;             // K2N*LD2
constexpr size_t F_YSC   = F_A2 + (size_t)K2N * LD2;   // N0*HID
constexpr size_t F_H0    = F_YSC + (size_t)N0 * HID;   // N0*HID
constexpr size_t F_H1    = F_H0 + (size_t)N0 * HID;    // K1N*HID
constexpr size_t F_H2    = F_H1 + (size_t)K1N * HID;   // K2N*HID
constexpr size_t F_U1    = F_H2 + (size_t)K2N * HID;   // (hole, kept for layout)
constexpr size_t F_U1B   = F_U1 + (size_t)K1N * HID;   // K1N*HID
constexpr size_t F_YF    = F_U1B + (size_t)K1N * HID;  // N0*3
constexpr size_t F_SCORE = F_YF + (size_t)N0 * 3;      // N0
constexpr size_t F_GATE1 = F_SCORE + N0;               // K1N  } contiguous zero fill
constexpr size_t F_GATE2 = F_GATE1 + K1N;              // K2N  }
constexpr size_t F_DIS0  = F_GATE2 + K2N;              // (unused)
constexpr size_t F_DIS1  = F_DIS0 + N0;                // K1N
constexpr size_t F_DIS2  = F_DIS1 + K1N;               // K2N
constexpr size_t F_PERM1 = F_DIS2 + K2N;               // K1N (int) } contiguous 0 fill
constexpr size_t F_PERM2 = F_PERM1 + K1N;              // K2N (int) }
constexpr size_t F_INV1  = F_PERM2 + K2N;              // N0  (int) } contiguous -1 fill
constexpr size_t F_INV2  = F_INV1 + N0;                // K1N (int) }
constexpr size_t F_CNTI  = F_INV2 + K1N;               // N0  (int) } contiguous 0 fill
constexpr size_t F_CNTO  = F_CNTI + N0;                // N0  (int) } (unused now)
constexpr size_t F_SELF  = F_CNTO + N0;                // N0  (int) }
constexpr size_t F_CI    = F_SELF + N0;                // N0*CAP (int)
constexpr size_t F_CO    = F_CI + (size_t)N0 * CAP;    // N0*CAP (int) (unused now)
constexpr size_t F_CSRN  = F_CO + (size_t)N0 * CAP;    // K1N (int)
constexpr size_t F_CSRK  = F_CSRN + K1N;               // K1N*RCAP (int)
constexpr size_t F_CSRW  = F_CSRK + (size_t)K1N * RCAP;// K1N*RCAP (float)
constexpr size_t F_END   = F_CSRW + (size_t)K1N * RCAP;

// ---------------- init: small fills only (A1 no longer needs zeroing) ----------------
__global__ void k_init(float* __restrict__ gate, int* __restrict__ perm,
                       int* __restrict__ inv, int* __restrict__ cnt,
                       float* __restrict__ outlab) {
  int i = blockIdx.x * blockDim.x + threadIdx.x, st = gridDim.x * blockDim.x;
  for (int j = i; j < K1N + K2N; j += st) gate[j] = 0.0f;
  for (int j = i; j < K1N + K2N; j += st) perm[j] = 0;
  for (int j = i; j < N0 + K1N; j += st) inv[j] = -1;
  for (int j = i; j < 3 * N0; j += st) cnt[j] = 0;
  for (int j = i; j < N0 * 29; j += st) outlab[j] = 0.0f;
}

// Build per-node in-edge lists only (out-lists no longer needed).
__global__ void k_count(const int* __restrict__ ei, int* cnt_in, int* selfc, int* col_in) {
  int e = blockIdx.x * blockDim.x + threadIdx.x;
  if (e >= E0) return;
  int s = ei[e], d = ei[E0 + e];
  if (s == d) { atomicAdd(&selfc[d], 1); return; }
  int a = atomicAdd(&cnt_in[d], 1);
  if (a < CAP) col_in[d * CAP + a] = s;
}

// Ysc[row][f] = scale(row) * sum_k Xeff[src(row)][k] * Wm[k][f]
__global__ __launch_bounds__(256) void k_yw2(const float* __restrict__ X,
                                             const float* __restrict__ X2,
                                             const int* __restrict__ inv2c,
                                             int Kin, int nsrc, int n,
                                             const float* __restrict__ Wm,
                                             const int* __restrict__ perm,
                                             const float* __restrict__ gate,
                                             const float* __restrict__ dis,
                                             const int* __restrict__ cntd,
                                             const int* __restrict__ selfd,
                                             float* __restrict__ Ysc) {
  __shared__ float Wt[32 * HID];   // 16 KB, [kk][f]
  __shared__ float Xt[32 * ATS];   // 4.6 KB, [kk][row] transposed
  int t = threadIdx.x;
  int r0 = blockIdx.x * BM;
  int f4 = (t & 31) * 4;
  int rg = t >> 5;                 // 0..7 -> rows r0 + rg*4 + {0..3}
  float4 acc0 = {0,0,0,0}, acc1 = {0,0,0,0}, acc2 = {0,0,0,0}, acc3 = {0,0,0,0};
  for (int kb = 0; kb < Kin; kb += 32) {
    {
      const float4* src = (const float4*)(Wm + (size_t)kb * HID);
      float4* dst = (float4*)Wt;
#pragma unroll
      for (int i = 0; i < 4; ++i) dst[i * 256 + t] = src[i * 256 + t];
    }
    {
      int j = t >> 3;
      int k4 = (t & 7) * 4;
      int r = r0 + j;
      int src_row = (r < n) ? r : (n - 1);
      if (perm) {
        int s = perm[src_row];
        if (s < 0) s = 0;
        if (s >= nsrc) s = nsrc - 1;
        src_row = s;
      }
      float4 xv = *(const float4*)(X + (size_t)src_row * Kin + kb + k4);
      if (X2) {
        int ii = inv2c[src_row];
        if (ii >= 0 && ii < K2N) {
          float4 x2 = *(const float4*)(X2 + (size_t)ii * Kin + kb + k4);
          xv.x += x2.x; xv.y += x2.y; xv.z += x2.z; xv.w += x2.w;
        }
      }
      Xt[(k4 + 0) * ATS + j] = xv.x;
      Xt[(k4 + 1) * ATS + j] = xv.y;
      Xt[(k4 + 2) * ATS + j] = xv.z;
      Xt[(k4 + 3) * ATS + j] = xv.w;
    }
    __syncthreads();
#pragma unroll 4
    for (int kk = 0; kk < 32; ++kk) {
      float4 y = *(const float4*)&Wt[kk * HID + f4];
      float4 a = *(const float4*)&Xt[kk * ATS + rg * 4];
      acc0.x += a.x * y.x; acc0.y += a.x * y.y; acc0.z += a.x * y.z; acc0.w += a.x * y.w;
      acc1.x += a.y * y.x; acc1.y += a.y * y.y; acc1.z += a.y * y.z; acc1.w += a.y * y.w;
      acc2.x += a.z * y.x; acc2.y += a.z * y.y; acc2.z += a.z * y.z; acc2.w += a.z * y.w;
      acc3.x += a.w * y.x; acc3.y += a.w * y.y; acc3.z += a.w * y.z; acc3.w += a.w * y.w;
    }
    __syncthreads();
  }
  int r = r0 + rg * 4;
  float4* accs[4] = {&acc0, &acc1, &acc2, &acc3};
#pragma unroll
  for (int j = 0; j < 4; ++j) {
    int row = r + j;
    if (row >= n) continue;
    float g = gate ? gate[row] : 1.0f;
    float d = dis ? dis[row] : (1.0f / sqrtf((float)(cntd[row] + selfd[row] + 2)));
    float s = d * g;
    float4 a = *accs[j];
    *(float4*)&Ysc[(size_t)row * HID + f4] = make_float4(s * a.x, s * a.y, s * a.z, s * a.w);
  }
}

// Level-0 sparse GCN + fused score (128 threads = 2 waves)
__global__ void k_gcn_sparse(const float* __restrict__ Ysc, const int* __restrict__ cnt_in,
                             const int* __restrict__ col_in, const int* __restrict__ selfc,
                             const float* __restrict__ bias, const float* __restrict__ p,
                             float* __restrict__ H, float* __restrict__ score) {
  __shared__ float red[HID];
  __shared__ float red2[HID];
  int d = blockIdx.x, f = threadIdx.x;
  int cntu = cnt_in[d];
  int cnt = cntu > CAP ? CAP : cntu;
  float acc = (2.0f + (float)selfc[d]) * Ysc[d * HID + f];
  int e = 0;
  for (; e + 8 <= cnt; e += 8) {   // ILP-8 gather, same accumulation order
    float y[8];
#pragma unroll
    for (int j = 0; j < 8; ++j) y[j] = Ysc[col_in[d * CAP + e + j] * HID + f];
#pragma unroll
    for (int j = 0; j < 8; ++j) acc += y[j];
  }
  for (; e < cnt; ++e) acc += Ysc[col_in[d * CAP + e] * HID + f];
  float d0 = 1.0f / sqrtf((float)(cntu + selfc[d] + 2));
  float h = tanhf(d0 * acc + bias[f]);
  H[d * HID + f] = h;
  float pv = p[f];
  red[f] = h * pv;
  red2[f] = pv * pv;
  __syncthreads();
  for (int s = 64; s > 0; s >>= 1) {
    if (f < s) { red[f] += red[f + s]; red2[f] += red2[f + s]; }
    __syncthreads();
  }
  if (f == 0) score[d] = tanhf(red[0] * (1.0f / sqrtf(red2[0])));
}

// Top-K, one 1024-thread block (round-1 verified).
__global__ __launch_bounds__(TKT) void k_topk(const float* __restrict__ score, int n, int K,
                                              int* __restrict__ perm, float* __restrict__ gatec,
                                              int* __restrict__ inv) {
  __shared__ unsigned setA[N0];
  __shared__ unsigned setB[N0];
  __shared__ int hist[256];
  __shared__ int sscan[257];
  __shared__ unsigned pfx_sh;
  __shared__ int rem_sh;
  __shared__ int cnt_sh;
  __shared__ int cgt[48], ceq[48], bgt[48], beq[48];
  int t = threadIdx.x;
  int lane = t & 63, wv = t >> 6;   // 16 waves
  unsigned long long below = (lane == 0) ? 0ull : (~0ull >> (64 - lane));
  for (int i = t; i < n; i += TKT) setA[i] = fkey(score[i]);
  __syncthreads();

  unsigned prefix = 0; int rem = K; int m = n;
  unsigned* cur = setA; unsigned* nxt = setB;
  for (int pass = 3; pass >= 0; --pass) {
    if (t < 256) hist[t] = 0;
    __syncthreads();
    for (int i = t; i < m; i += TKT) atomicAdd(&hist[(cur[i] >> (pass * 8)) & 255], 1);
    __syncthreads();
    if (t < 256) { sscan[t] = hist[t]; if (t == 0) sscan[256] = 0; }
    __syncthreads();
    for (int off = 1; off < 256; off <<= 1) {
      int add = 0;
      if (t < 256) add = (t + off < 256) ? sscan[t + off] : 0;
      __syncthreads();
      if (t < 256) sscan[t] += add;
      __syncthreads();
    }
    if (t < 256 && sscan[t] >= rem && sscan[t + 1] < rem) {
      pfx_sh = prefix | ((unsigned)t << (pass * 8));
      rem_sh = rem - sscan[t + 1];
    }
    __syncthreads();
    prefix = pfx_sh; rem = rem_sh;
    if (pass > 0) {
      unsigned dg = (prefix >> (pass * 8)) & 255u;
      if (t == 0) cnt_sh = 0;
      __syncthreads();
      for (int c0 = 0; c0 < m; c0 += TKT) {
        int i = c0 + t;
        unsigned u = (i < m) ? cur[i] : 0u;
        bool match = (i < m) && (((u >> (pass * 8)) & 255u) == dg);
        unsigned long long mm = __ballot(match);
        int cw = (int)__popcll(mm);
        int basew = 0;
        if (lane == 0 && cw) basew = atomicAdd(&cnt_sh, cw);
        basew = __shfl(basew, 0);
        if (match) nxt[basew + (int)__popcll(mm & below)] = u;
      }
      __syncthreads();
      m = cnt_sh;
      unsigned* tmp = cur; cur = nxt; nxt = tmp;
    }
  }
  unsigned uthr = prefix;
  int c_gt = K - rem;
  int NC = (n + 63) >> 6;           // <= 47 chunks of 64
  for (int c = wv; c < NC; c += 16) {
    int i = (c << 6) + lane;
    unsigned u = (i < n) ? fkey(score[i]) : 0u;
    bool isgt = (i < n) && (u > uthr);
    bool iseq = (i < n) && (u == uthr);
    unsigned long long mg = __ballot(isgt);
    unsigned long long me = __ballot(iseq);
    if (lane == 0) { cgt[c] = (int)__popcll(mg); ceq[c] = (int)__popcll(me); }
  }
  __syncthreads();
  if (t == 0) {
    int g = 0, e = 0;
    for (int c = 0; c < NC; ++c) { bgt[c] = g; g += cgt[c]; beq[c] = e; e += ceq[c]; }
  }
  __syncthreads();
  for (int c = wv; c < NC; c += 16) {
    int i = (c << 6) + lane;
    unsigned u = (i < n) ? fkey(score[i]) : 0u;
    bool isgt = (i < n) && (u > uthr);
    bool iseq = (i < n) && (u == uthr);
    unsigned long long mg = __ballot(isgt);
    unsigned long long me = __ballot(iseq);
    if (isgt) {
      int pos = bgt[c] + (int)__popcll(mg & below);
      perm[pos] = i; gatec[pos] = inv_fkey(u); inv[i] = pos;
    } else if (iseq) {
      int er = beq[c] + (int)__popcll(me & below);
      if (er < rem) { int pos = c_gt + er; perm[pos] = i; gatec[pos] = inv_fkey(u); inv[i] = pos; }
    }
  }
}

// Row-wise A1 build (replaces k_pairs + k_a1csr + the dense A1 zero-fill):
// A1[r][jj] = 2*#edges(perm[jj]->d) + sum_{m in in(d)} #edges(perm[jj]->m), jj != r's node.
// Built as ints in LDS (order-free, exact), then compacted to CSR (ascending,
// identical order/values to the old path), dense row written, dis1 fused.
__global__ __launch_bounds__(256) void k_rowcsr(const int* __restrict__ perm1,
                                                const int* __restrict__ inv1,
                                                const int* __restrict__ cnt_in,
                                                const int* __restrict__ col_in,
                                                float* __restrict__ A1,
                                                int* __restrict__ csr_n,
                                                int* __restrict__ csr_k,
                                                float* __restrict__ csr_w,
                                                float* __restrict__ dis1) {
  __shared__ int row[K1N];
  __shared__ int cntw[4];
  __shared__ int wsum_sh;
  int r = blockIdx.x, t = threadIdx.x;
  for (int i = t; i < K1N; i += 256) row[i] = 0;
  if (t == 0) wsum_sh = 0;
  __syncthreads();
  int d = perm1[r];
  int ni = cnt_in[d]; if (ni > CAP) ni = CAP;
  // +2*A' term (one thread per in-edge entry; col_in excludes self-loops)
  if (t < ni) {
    int s = col_in[d * CAP + t];
    int jj = inv1[s];
    if (jj >= 0) atomicAdd(&row[jj], 2);
  }
  // middle term: a over in-edges of d (32 lanes), b over in-edges of m (8 lanes)
  {
    int ta = t >> 3, tb = t & 7;
    for (int a = ta; a < ni; a += 32) {
      int m = col_in[d * CAP + a];
      int nm = cnt_in[m]; if (nm > CAP) nm = CAP;
      for (int b = tb; b < nm; b += 8) {
        int s = col_in[m * CAP + b];
        if (s != d) {
          int jj = inv1[s];
          if (jj >= 0) atomicAdd(&row[jj], 1);
        }
      }
    }
  }
  __syncthreads();
  // compact to CSR (ascending cols) + dense row write + int-exact rowsum
  int wid = t >> 6, lane = t & 63;
  unsigned long long below = (lane == 0) ? 0ull : (~0ull >> (64 - lane));
  int base = 0, ws = 0;
  int* gk = csr_k + (size_t)r * RCAP;
  float* gw = csr_w + (size_t)r * RCAP;
  float* arow = A1 + (size_t)r * LD1;
  for (int c0 = 0; c0 < K1N; c0 += 256) {
    int col = c0 + t;
    int v = (col < K1N) ? row[col] : 0;
    ws += v;
    bool nz = (v != 0);
    unsigned long long m = __ballot(nz);
    if (lane == 0) cntw[wid] = (int)__popcll(m);
    __syncthreads();
    int pref = 0;
#pragma unroll
    for (int w = 0; w < 4; ++w) if (w < wid) pref += cntw[w];
    int pos = base + pref + (int)__popcll(m & below);
    if (nz) { gk[pos] = col; gw[pos] = (float)v; }
    if (col < K1N) arow[col] = (float)v;
    base += cntw[0] + cntw[1] + cntw[2] + cntw[3];
    __syncthreads();
  }
  for (int off = 32; off > 0; off >>= 1) ws += __shfl_down(ws, off);
  if (lane == 0) atomicAdd(&wsum_sh, ws);
  __syncthreads();
  if (t == 0) {
    csr_n[r] = base;
    dis1[r] = 1.0f / sqrtf((float)wsum_sh + 2.0f);
  }
}

// Column compaction to int16: Ac[k][b] = (short)A1[k][perm2[b]]  (b < K2N, else 0)
__global__ __launch_bounds__(256) void k_cmp(const float* __restrict__ A1,
                                             const int* __restrict__ perm2,
                                             short* __restrict__ Ac) {
  __shared__ int q[K2N];
  int k = blockIdx.x, t = threadIdx.x;
  for (int i = t; i < K2N; i += 256) {
    int v = perm2[i];
    if (v < 0) v = 0;
    if (v >= K1N) v = K1N - 1;
    q[i] = v;
  }
  __syncthreads();
  const float* row = A1 + (size_t)k * LD1;
  short* dst = Ac + (size_t)k * LD2;
  for (int b = t; b < LD2; b += 256) dst[b] = (b < K2N) ? (short)row[q[b]] : (short)0;
}

// A2[a][b] = (b!=a) ? sum_k A1[qa][k]*Ac[k][b] + 2*A1[qa][perm2[b]] : 0
// 192 threads (all active); CSR row nonzeros; int16 Ac, ILP-8; fused dis2.
__global__ __launch_bounds__(192) void k_sq2(const float* __restrict__ A1,
                                             const short* __restrict__ Ac,
                                             const int* __restrict__ perm2,
                                             const int* __restrict__ csr_n,
                                             const int* __restrict__ csr_k,
                                             const float* __restrict__ csr_w,
                                             float* __restrict__ A2,
                                             float* __restrict__ dis2) {
  __shared__ int klist[K1N];
  __shared__ float wlist[K1N];
  __shared__ float wred[3];
  int a = blockIdx.x, t = threadIdx.x;
  int qa = perm2[a];
  if (qa < 0) qa = 0;
  if (qa >= K1N) qa = K1N - 1;
  const float* arow = A1 + (size_t)qa * LD1;
  int nnz = csr_n[qa];
  {
    const int* gk = csr_k + (size_t)qa * RCAP;
    const float* gw = csr_w + (size_t)qa * RCAP;
    for (int c = t; c < nnz; c += 192) { klist[c] = gk[c]; wlist[c] = gw[c]; }
  }
  __syncthreads();
  int c0 = t * 4;                     // 0..764, always in-range
  float4 acc = make_float4(0.f, 0.f, 0.f, 0.f);
  int p = 0;
  for (; p + 8 <= nnz; p += 8) {      // 8 independent L2 loads in flight
    int kk[8]; float ww[8];
#pragma unroll
    for (int j = 0; j < 8; ++j) { kk[j] = klist[p + j]; ww[j] = wlist[p + j]; }
    short4 v[8];
#pragma unroll
    for (int j = 0; j < 8; ++j) v[j] = *(const short4*)&Ac[(size_t)kk[j] * LD2 + c0];
#pragma unroll
    for (int j = 0; j < 8; ++j) {
      acc.x += ww[j] * (float)v[j].x;
      acc.y += ww[j] * (float)v[j].y;
      acc.z += ww[j] * (float)v[j].z;
      acc.w += ww[j] * (float)v[j].w;
    }
  }
  for (; p < nnz; ++p) {
    int k = klist[p]; float w = wlist[p];
    short4 v = *(const short4*)&Ac[(size_t)k * LD2 + c0];
    acc.x += w * (float)v.x; acc.y += w * (float)v.y;
    acc.z += w * (float)v.z; acc.w += w * (float)v.w;
  }
  float rsum = 0.0f;
  {
    float accv[4] = {acc.x, acc.y, acc.z, acc.w};
    float outv[4];
#pragma unroll
    for (int j = 0; j < 4; ++j) {
      int col = c0 + j;
      float v = 0.0f;
      if (col < K2N && col != a) {
        int qb = perm2[col];
        if (qb < 0) qb = 0;
        if (qb >= K1N) qb = K1N - 1;
        v = accv[j] + 2.0f * arow[qb];
      }
      outv[j] = v;
      rsum += v;
    }
    *(float4*)&A2[(size_t)a * LD2 + c0] = make_float4(outv[0], outv[1], outv[2], outv[3]);
  }
  for (int off = 32; off > 0; off >>= 1) rsum += __shfl_down(rsum, off);
  if ((t & 63) == 0) wred[t >> 6] = rsum;
  __syncthreads();
  if (t == 0) dis2[a] = 1.0f / sqrtf(wred[0] + wred[1] + wred[2] + 2.0f);
}

// CSR-based row-sparse GCN aggregation + epilogue (+ optional fused score).
__global__ __launch_bounds__(128) void k_spmv_csr(const int* __restrict__ csr_n,
                                                  const int* __restrict__ csr_k,
                                                  const float* __restrict__ csr_w,
                                                  const float* __restrict__ Ysc,
                                                  const float* __restrict__ dis,
                                                  const float* __restrict__ bias,
                                                  const float* __restrict__ p,
                                                  float* __restrict__ H,
                                                  float* __restrict__ score, int act) {
  __shared__ int klist[K1N];
  __shared__ float wlist[K1N];
  __shared__ float red[HID];
  __shared__ float red2[HID];
  int r = blockIdx.x, t = threadIdx.x;
  int nnz = csr_n[r];
  {
    const int* gk = csr_k + (size_t)r * RCAP;
    const float* gw = csr_w + (size_t)r * RCAP;
    for (int i = t; i < nnz; i += 128) { klist[i] = gk[i]; wlist[i] = gw[i]; }
  }
  __syncthreads();
  float acc = 0.0f;
  int pp = 0;
  for (; pp + 8 <= nnz; pp += 8) {
    float y[8];
#pragma unroll
    for (int j = 0; j < 8; ++j) y[j] = Ysc[(size_t)klist[pp + j] * HID + t];
#pragma unroll
    for (int j = 0; j < 8; ++j) acc += wlist[pp + j] * y[j];
  }
  for (; pp < nnz; ++pp) acc += wlist[pp] * Ysc[(size_t)klist[pp] * HID + t];
  float zv = dis[r] * (acc + 2.0f * Ysc[(size_t)r * HID + t]) + bias[t];
  float h = act ? tanhf(zv) : zv;
  H[(size_t)r * HID + t] = h;
  if (p) {
    float pv = p[t];
    red[t] = h * pv;
    red2[t] = pv * pv;
    __syncthreads();
    for (int s = 64; s > 0; s >>= 1) {
      if (t < s) { red[t] += red[t + s]; red2[t] += red2[t + s]; }
      __syncthreads();
    }
    if (t == 0) score[r] = tanhf(red[0] * (1.0f / sqrtf(red2[0])));
  }
}

// Dense direct spmv for A2 (~93% dense rows): all cols ascending.
// Bit-exact vs the old nonzero-compacted scan: interleaved +0 terms leave acc
// unchanged (IEEE x+(+/-0)=x, +0 start), nonzero subsequence in same order.
__global__ __launch_bounds__(128) void k_spmv2(const float* __restrict__ A2,
                                               const float* __restrict__ Ysc,
                                               const float* __restrict__ dis2,
                                               const float* __restrict__ bias,
                                               float* __restrict__ H) {
  int r = blockIdx.x, t = threadIdx.x;
  const float* arow = A2 + (size_t)r * LD2;
  float acc = 0.0f;
  int c = 0;
  for (; c + 8 <= K2N; c += 8) {
    float w[8], y[8];
#pragma unroll
    for (int j = 0; j < 8; ++j) w[j] = arow[c + j];
#pragma unroll
    for (int j = 0; j < 8; ++j) y[j] = Ysc[(size_t)(c + j) * HID + t];
#pragma unroll
    for (int j = 0; j < 8; ++j) acc += w[j] * y[j];
  }
  for (; c < K2N; ++c) acc += arow[c] * Ysc[(size_t)c * HID + t];
  float zv = dis2[r] * (acc + 2.0f * Ysc[(size_t)r * HID + t]) + bias[t];
  H[(size_t)r * HID + t] = tanhf(zv);
}

// Yfsc[i] = dis0[i] * ((h0[i] + scatter(u1b)) @ W_up1)   [N0 x 3]
__global__ void k_yf(const float* __restrict__ h0, const float* __restrict__ u1b,
                     const int* __restrict__ inv1, const float* __restrict__ Wup1,
                     const int* __restrict__ cnt_in, const int* __restrict__ selfc,
                     float* __restrict__ Yfsc) {
  __shared__ float red[3][HID];
  int i = blockIdx.x, t = threadIdx.x;
  float v = h0[i * HID + t];
  int ii = inv1[i];
  if (ii >= 0 && ii < K1N) v += u1b[ii * HID + t];
#pragma unroll
  for (int c = 0; c < 3; ++c) red[c][t] = v * Wup1[t * 3 + c];
  __syncthreads();
  for (int s = 64; s > 0; s >>= 1) {
    if (t < s) { red[0][t] += red[0][t + s]; red[1][t] += red[1][t + s]; red[2][t] += red[2][t + s]; }
    __syncthreads();
  }
  if (t < 3) {
    float d0 = 1.0f / sqrtf((float)(cnt_in[i] + selfc[i] + 2));
    Yfsc[i * 3 + t] = d0 * red[t][0];
  }
}

__global__ void k_final(const float* __restrict__ Yfsc, const int* __restrict__ cnt_in,
                        const int* __restrict__ col_in, const int* __restrict__ selfc,
                        const float* __restrict__ bup1, const float* __restrict__ z,
                        float* __restrict__ out) {
  int idx = blockIdx.x * blockDim.x + threadIdx.x;
  if (idx >= N0 * 3) return;
  int d = idx / 3, c = idx - d * 3;
  int cntu = cnt_in[d];
  int cnt = cntu > CAP ? CAP : cntu;
  float acc = (2.0f + (float)selfc[d]) * Yfsc[d * 3 + c];
  int e = 0;
  for (; e + 8 <= cnt; e += 8) {   // ILP-8 gather, same accumulation order
    float y[8];
#pragma unroll
    for (int j = 0; j < 8; ++j) y[j] = Yfsc[col_in[d * CAP + e + j] * 3 + c];
#pragma unroll
    for (int j = 0; j < 8; ++j) acc += y[j];
  }
  for (; e < cnt; ++e) acc += Yfsc[col_in[d * CAP + e] * 3 + c];
  float d0 = 1.0f / sqrtf((float)(cntu + selfc[d] + 2));
  out[idx] = d0 * acc + bup1[c] + 0.1f * z[idx];
}

extern "C" void kernel_launch(void* const* d_in, const int* in_sizes, int n_in,
                              void* d_out, int out_size, void* d_ws, size_t ws_size,
                              hipStream_t stream) {
  const float* x   = (const float*)d_in[0];
  const float* z   = (const float*)d_in[1];
  const float* Wd0 = (const float*)d_in[2];
  const float* bd0 = (const float*)d_in[3];
  const float* Wd1 = (const float*)d_in[4];
  const float* bd1 = (const float*)d_in[5];
  const float* Wd2 = (const float*)d_in[6];
  const float* bd2 = (const float*)d_in[7];
  const float* p1  = (const float*)d_in[8];
  const float* p2  = (const float*)d_in[9];
  const float* Wu0 = (const float*)d_in[10];
  const float* bu0 = (const float*)d_in[11];
  const float* Wu1 = (const float*)d_in[12];
  const float* bu1 = (const float*)d_in[13];
  const int*   ei  = (const int*)d_in[14];

  if (ws_size < F_END * sizeof(float)) return;

  float* W     = (float*)d_ws;
  float* A1    = W + F_A1;
  short* Ac    = (short*)(W + F_SCR);
  float* A2    = W + F_A2;
  float* Ysc   = W + F_YSC;
  float* h0    = W + F_H0;
  float* h1    = W + F_H1;
  float* h2    = W + F_H2;
  float* u1b   = W + F_U1B;
  float* Yfsc  = W + F_YF;
  float* score = W + F_SCORE;
  float* gate1 = W + F_GATE1;
  float* gate2 = W + F_GATE2;
  float* dis1  = W + F_DIS1;
  float* dis2  = W + F_DIS2;
  int* perm1   = (int*)(W + F_PERM1);
  int* perm2   = (int*)(W + F_PERM2);
  int* inv1    = (int*)(W + F_INV1);
  int* inv2    = (int*)(W + F_INV2);
  int* cnt_in  = (int*)(W + F_CNTI);
  int* selfc   = (int*)(W + F_SELF);
  int* col_in  = (int*)(W + F_CI);
  int* csr_n   = (int*)(W + F_CSRN);
  int* csr_k   = (int*)(W + F_CSRK);
  float* csr_w = W + F_CSRW;
  float* out   = (float*)d_out;

  // ---- init (small fills only; dense A1 is fully overwritten by k_rowcsr) ----
  k_init<<<128, 256, 0, stream>>>(gate1, perm1, inv1, cnt_in, out + N0 * 3);

  // ---- in-edge lists ----
  k_count<<<(E0 + 255) / 256, 256, 0, stream>>>(ei, cnt_in, selfc, col_in);

  // ---- level 0 GCN + pool-1 score ----
  k_yw2<<<(N0 + BM - 1) / BM, 256, 0, stream>>>(x, nullptr, nullptr, 32, N0, N0, Wd0,
                                                nullptr, nullptr, nullptr, cnt_in, selfc, Ysc);
  k_gcn_sparse<<<N0, HID, 0, stream>>>(Ysc, cnt_in, col_in, selfc, bd0, p1, h0, score);
  k_topk<<<1, TKT, 0, stream>>>(score, N0, K1N, perm1, gate1, inv1);

  // ---- A1 rows: build + CSR + dense + dis1 in ONE kernel ----
  k_rowcsr<<<K1N, 256, 0, stream>>>(perm1, inv1, cnt_in, col_in, A1, csr_n, csr_k, csr_w, dis1);

  // ---- level 1 GCN (CSR spmv) + pool-2 score fused ----
  k_yw2<<<(K1N + BM - 1) / BM, 256, 0, stream>>>(h0, nullptr, nullptr, HID, N0, K1N, Wd1,
                                                 perm1, gate1, dis1, nullptr, nullptr, Ysc);
  k_spmv_csr<<<K1N, 128, 0, stream>>>(csr_n, csr_k, csr_w, Ysc, dis1, bd1, p2, h1, score, 1);
  k_topk<<<1, TKT, 0, stream>>>(score, K1N, K2N, perm2, gate2, inv2);

  // ---- A2 = augment(A1)[perm2][:,perm2] (int16 Ac + CSR row + fused dis2) ----
  k_cmp<<<K1N, 256, 0, stream>>>(A1, perm2, Ac);
  k_sq2<<<K2N, 192, 0, stream>>>(A1, Ac, perm2, csr_n, csr_k, csr_w, A2, dis2);

  // ---- level 2 GCN (dense direct spmv on A2) ----
  k_yw2<<<(K2N + BM - 1) / BM, 256, 0, stream>>>(h1, nullptr, nullptr, HID, K1N, K2N, Wd2,
                                                 perm2, gate2, dis2, nullptr, nullptr, Ysc);
  k_spmv2<<<K2N, 128, 0, stream>>>(A2, Ysc, dis2, bd2, h2);

  // ---- up path (combine fused into staging; CSR spmv) ----
  k_yw2<<<(K1N + BM - 1) / BM, 256, 0, stream>>>(h1, h2, inv2, HID, K1N, K1N, Wu0,
                                                 nullptr, nullptr, dis1, nullptr, nullptr, Ysc);
  k_spmv_csr<<<K1N, 128, 0, stream>>>(csr_n, csr_k, csr_w, Ysc, dis1, bu0, nullptr, u1b, nullptr, 1);

  // ---- final ----
  k_yf<<<N0, HID, 0, stream>>>(h0, u1b, inv1, Wu1, cnt_in, selfc, Yfsc);
  k_final<<<(N0 * 3 + 255) / 256, 256, 0, stream>>>(Yfsc, cnt_in, col_in, selfc, bu1, z, out);
}